// Round 1
// 61.580 us; speedup vs baseline: 1.0114x; 1.0114x over previous
//
#include <hip/hip_runtime.h>

// PeerNet: out = relu-MLP with per-feature kNN-mean (k=6, 1D) in the middle.
// B=4096, D=1024, H1=128, H2=64, O=2. All fp32.
// gemm1 now runs on MFMA via f16 hi/lo split (Markidis): fp32-comparable
// accuracy, 3x f16 MFMA; kills split-K partials + reduce kernel.

#define NB   4096
#define DIN  1024
#define NH1  128
#define NH2  64

typedef _Float16 f16x8 __attribute__((ext_vector_type(8)));
typedef _Float16 f16x4 __attribute__((ext_vector_type(4)));
typedef float    f32x4 __attribute__((ext_vector_type(4)));

// ---------------------------------------------------------------------------
// prep: W1 [128][1024] fp32 -> Whi/Wlo f16 (hi = rn(w), lo = rn(w - hi)).
// 32768 threads, 4 elems each.
// ---------------------------------------------------------------------------
__global__ __launch_bounds__(256) void prep_w1(const float* __restrict__ W1,
                                               _Float16* __restrict__ Whi,
                                               _Float16* __restrict__ Wlo)
{
    const int i = (blockIdx.x * 256 + threadIdx.x) * 4;
    const float4 v = *(const float4*)&W1[i];
    const _Float16 h0 = (_Float16)v.x, h1 = (_Float16)v.y;
    const _Float16 h2 = (_Float16)v.z, h3 = (_Float16)v.w;
    f16x4 hv = {h0, h1, h2, h3};
    f16x4 lv = {(_Float16)(v.x - (float)h0), (_Float16)(v.y - (float)h1),
                (_Float16)(v.z - (float)h2), (_Float16)(v.w - (float)h3)};
    *(f16x4*)&Whi[i] = hv;
    *(f16x4*)&Wlo[i] = lv;
}

// ---------------------------------------------------------------------------
// GEMM1 via MFMA 16x16x32 f16, hi/lo split: h1T[n][m] = relu(x@W1^T + b1)^T.
// Grid 256 blocks x 512 threads (8 waves). Block: 16 batch rows, all 128 n.
// Stage x rows into LDS as hi/lo f16 (stride 1032 f16: rows step 4 banks ->
// 2-way on ds_read_b128 = free). Wave w owns n-tile n0=w*16, full K=1024.
// Per k-step (K=32): 2 ds_read_b128 (A hi/lo) + 2 global 16B (W1 hi/lo,
// L2-resident) + 3 MFMA (hihi + hilo + lohi).
// C-frag: row m=(lane>>4)*4+reg, col n=lane&15 -> float4 store to h1T.
// ---------------------------------------------------------------------------
__global__ __launch_bounds__(512) void gemm1_mfma(const float* __restrict__ x,
                                                  const _Float16* __restrict__ Whi,
                                                  const _Float16* __restrict__ Wlo,
                                                  const float* __restrict__ b1,
                                                  float* __restrict__ h1T)
{
    __shared__ _Float16 xhi[16 * 1032];
    __shared__ _Float16 xlo[16 * 1032];
    const int tid = threadIdx.x;
    const int m0  = blockIdx.x * 16;

    {   // stage + convert: thread t -> row t>>5, cols (t&31)*4 + i*128
        const int r  = tid >> 5;
        const int kb = (tid & 31) * 4;
#pragma unroll
        for (int i = 0; i < 8; ++i) {
            const int k = kb + i * 128;
            const float4 v = *(const float4*)&x[(size_t)(m0 + r) * DIN + k];
            const _Float16 h0 = (_Float16)v.x, h1 = (_Float16)v.y;
            const _Float16 h2 = (_Float16)v.z, h3 = (_Float16)v.w;
            f16x4 hv = {h0, h1, h2, h3};
            f16x4 lv = {(_Float16)(v.x - (float)h0), (_Float16)(v.y - (float)h1),
                        (_Float16)(v.z - (float)h2), (_Float16)(v.w - (float)h3)};
            *(f16x4*)&xhi[r * 1032 + k] = hv;
            *(f16x4*)&xlo[r * 1032 + k] = lv;
        }
    }
    __syncthreads();

    const int lane = tid & 63;
    const int w    = tid >> 6;          // 0..7 -> n-tile
    const int n0   = w * 16;
    const int fr   = lane & 15;
    const int fq   = lane >> 4;         // 0..3

    f32x4 acc = {0.f, 0.f, 0.f, 0.f};
    const _Float16* __restrict__ whp = &Whi[(size_t)(n0 + fr) * DIN + fq * 8];
    const _Float16* __restrict__ wlp = &Wlo[(size_t)(n0 + fr) * DIN + fq * 8];
    const _Float16* xh = &xhi[fr * 1032 + fq * 8];
    const _Float16* xl = &xlo[fr * 1032 + fq * 8];

#pragma unroll 4
    for (int ks = 0; ks < 32; ++ks) {
        const int k = ks * 32;
        const f16x8 ah = *(const f16x8*)&xh[k];
        const f16x8 al = *(const f16x8*)&xl[k];
        const f16x8 bh = *(const f16x8*)&whp[k];
        const f16x8 bl = *(const f16x8*)&wlp[k];
        acc = __builtin_amdgcn_mfma_f32_16x16x32_f16(ah, bh, acc, 0, 0, 0);
        acc = __builtin_amdgcn_mfma_f32_16x16x32_f16(ah, bl, acc, 0, 0, 0);
        acc = __builtin_amdgcn_mfma_f32_16x16x32_f16(al, bh, acc, 0, 0, 0);
    }

    const int n = n0 + fr;
    const float bv = b1[n];
    float4 o;
    o.x = fmaxf(acc[0] + bv, 0.f);
    o.y = fmaxf(acc[1] + bv, 0.f);
    o.z = fmaxf(acc[2] + bv, 0.f);
    o.w = fmaxf(acc[3] + bv, 0.f);
    *(float4*)&h1T[(size_t)n * NB + m0 + fq * 4] = o;
}

// ---------------------------------------------------------------------------
// kNN stage 1: bitonic-sort each half-column (2048) — hybrid LDS/shuffle.
// ---------------------------------------------------------------------------
__global__ __launch_bounds__(512) void sort_half_kernel(const float* __restrict__ h1T,
                                                        float* __restrict__ sorted)
{
    __shared__ float s[2048];
    const int t = threadIdx.x;
    const int col  = blockIdx.x >> 1;
    const int half = blockIdx.x & 1;
    const float* __restrict__ src = h1T + (size_t)col * NB + half * 2048;

    float v[4];
#pragma unroll
    for (int q = 0; q < 4; ++q) v[q] = src[t + q * 512];

    // k = 2..64 entirely in registers (0 barriers)
#pragma unroll
    for (int k = 2; k <= 64; k <<= 1) {
#pragma unroll
        for (int j = k >> 1; j > 0; j >>= 1) {
#pragma unroll
            for (int q = 0; q < 4; ++q) {
                const int i = q * 512 + t;
                const float p = __shfl_xor(v[q], j);
                const bool up  = ((i & k) == 0);
                const bool low = ((i & j) == 0);
                v[q] = (low == up) ? fminf(v[q], p) : fmaxf(v[q], p);
            }
        }
    }
#pragma unroll
    for (int q = 0; q < 4; ++q) s[t + q * 512] = v[q];
    __syncthreads();

    for (int k = 128; k <= 2048; k <<= 1) {
        for (int j = k >> 1; j >= 64; j >>= 1) {
#pragma unroll
            for (int p = 0; p < 2; ++p) {
                const int c = t + p * 512;
                const int i = ((c & ~(j - 1)) << 1) | (c & (j - 1));
                const int ixj = i | j;
                const float a = s[i], b = s[ixj];
                const bool up = ((i & k) == 0);
                if ((a > b) == up) { s[i] = b; s[ixj] = a; }
            }
            __syncthreads();
        }
        // j = 32..1 in registers
#pragma unroll
        for (int q = 0; q < 4; ++q) v[q] = s[t + q * 512];
#pragma unroll
        for (int j = 32; j > 0; j >>= 1) {
#pragma unroll
            for (int q = 0; q < 4; ++q) {
                const int i = q * 512 + t;
                const float p = __shfl_xor(v[q], j);
                const bool up  = ((i & k) == 0);
                const bool low = ((i & j) == 0);
                v[q] = (low == up) ? fminf(v[q], p) : fmaxf(v[q], p);
            }
        }
#pragma unroll
        for (int q = 0; q < 4; ++q) s[t + q * 512] = v[q];
        __syncthreads();
    }

    float* __restrict__ dst = sorted + (size_t)col * NB + half * 2048;
#pragma unroll
    for (int q = 0; q < 4; ++q) dst[t + q * 512] = s[t + q * 512];
}

// ---------------------------------------------------------------------------
// kNN stage 2: 2 blocks per column (grid 256). Each block re-merges the two
// sorted halves via binary-search ranks (stable), then runs the 6-window
// phase on ITS half of the original elements (2/thread).
// ---------------------------------------------------------------------------
__global__ __launch_bounds__(1024) void knn_merge_kernel(const float* __restrict__ h1T,
                                                         const float* __restrict__ sorted,
                                                         float* __restrict__ prtT)
{
    __shared__ float sin_[NB];
    __shared__ float s[NB];
    const int col  = blockIdx.x >> 1;
    const int half = blockIdx.x & 1;
    const float* __restrict__ src = sorted + (size_t)col * NB;
#pragma unroll
    for (int p = 0; p < 4; ++p) sin_[threadIdx.x + p * 1024] = src[threadIdx.x + p * 1024];
    __syncthreads();

#pragma unroll
    for (int p = 0; p < 2; ++p) {
        const int j = threadIdx.x + p * 1024;   // 0..2047
        {   // half0 element: rank = j + #(half1 < v)
            const float v = sin_[j];
            int lo = 0, hi = 2048;
            while (lo < hi) { const int mid = (lo + hi) >> 1; if (sin_[2048 + mid] < v) lo = mid + 1; else hi = mid; }
            s[j + lo] = v;
        }
        {   // half1 element: rank = j + #(half0 <= v)
            const float v = sin_[2048 + j];
            int lo = 0, hi = 2048;
            while (lo < hi) { const int mid = (lo + hi) >> 1; if (sin_[mid] <= v) lo = mid + 1; else hi = mid; }
            s[j + lo] = v;
        }
    }
    __syncthreads();

    const float* __restrict__ colp = h1T + (size_t)col * NB;
#pragma unroll
    for (int p = 0; p < 2; ++p) {
        const int e   = half * 2048 + threadIdx.x + p * 1024;
        const float v = colp[e];
        int lo = 0, hi = NB;
        while (lo < hi) {
            const int mid = (lo + hi) >> 1;
            if (s[mid] < v) lo = mid + 1; else hi = mid;
        }
        int l = lo, h = lo;
        float sum = v;  // self
#pragma unroll
        for (int it = 0; it < 5; ++it) {
            const int li = (l > 0) ? l - 1 : 0;
            const int ri = (h < NB - 1) ? h + 1 : NB - 1;
            const float sl = s[li];
            const float sr = s[ri];
            const float dl = (l > 0) ? (v - sl) : 1e30f;
            const float dr = (h < NB - 1) ? (sr - v) : 1e30f;
            if (dl <= dr) { sum += sl; l = li; }
            else          { sum += sr; h = ri; }
        }
        prtT[(size_t)col * NB + e] = sum * (1.0f / 6.0f);
    }
}

// ---------------------------------------------------------------------------
// Fused tail: out = (relu(relu(prT^T @ Wpr^T + bpr) @ W2^T + b2)) @ Wo^T + bo
// ---------------------------------------------------------------------------
__global__ __launch_bounds__(256) void tail_kernel(const float* __restrict__ AT,
                                                   const float* __restrict__ Wpr,
                                                   const float* __restrict__ bpr,
                                                   const float* __restrict__ W2,
                                                   const float* __restrict__ b2,
                                                   const float* __restrict__ Wo,
                                                   const float* __restrict__ bo,
                                                   float* __restrict__ out)
{
    __shared__ float As[NH1 * 17];   // A^T tile [k=128][m=16]
    __shared__ float Bs[32 * 132];   // weight chunk staging (transposed)
    __shared__ float Ps[16 * 132];   // pr tile [m][n=128]
    __shared__ float Rs[16 * 32];    // out reduction [g][m*2+o]
    const int tid = threadIdx.x;
    const int m0  = blockIdx.x * 16;

    {
        const int row = tid >> 2;
        const int f   = (tid & 3) * 4;
#pragma unroll
        for (int h = 0; h < 2; ++h) {
            const int k = row + h * 64;
            const float4 v = *(const float4*)&AT[(size_t)k * NB + m0 + f];
            As[k * 17 + f + 0] = v.x;
            As[k * 17 + f + 1] = v.y;
            As[k * 17 + f + 2] = v.z;
            As[k * 17 + f + 3] = v.w;
        }
    }

    const int m  = tid & 15;
    const int g  = tid >> 4;     // 0..15
    const int n0 = g * 8;

    float acc[8];
#pragma unroll
    for (int j = 0; j < 8; ++j) acc[j] = 0.f;

    for (int k0 = 0; k0 < NH1; k0 += 32) {
        {   // Bs[kk][n] = Wpr[n][k0+kk]
            const int n  = tid >> 1;
            const int ko = (tid & 1) * 16;
#pragma unroll
            for (int i4 = 0; i4 < 4; ++i4) {
                const float4 v = *(const float4*)&Wpr[(size_t)n * NH1 + k0 + ko + i4 * 4];
                Bs[(ko + i4 * 4 + 0) * 132 + n] = v.x;
                Bs[(ko + i4 * 4 + 1) * 132 + n] = v.y;
                Bs[(ko + i4 * 4 + 2) * 132 + n] = v.z;
                Bs[(ko + i4 * 4 + 3) * 132 + n] = v.w;
            }
        }
        __syncthreads();
#pragma unroll
        for (int kk = 0; kk < 32; ++kk) {
            const float a   = As[(k0 + kk) * 17 + m];
            const float4 b0 = *(const float4*)&Bs[kk * 132 + n0];
            const float4 b1 = *(const float4*)&Bs[kk * 132 + n0 + 4];
            acc[0] = fmaf(a, b0.x, acc[0]);
            acc[1] = fmaf(a, b0.y, acc[1]);
            acc[2] = fmaf(a, b0.z, acc[2]);
            acc[3] = fmaf(a, b0.w, acc[3]);
            acc[4] = fmaf(a, b1.x, acc[4]);
            acc[5] = fmaf(a, b1.y, acc[5]);
            acc[6] = fmaf(a, b1.z, acc[6]);
            acc[7] = fmaf(a, b1.w, acc[7]);
        }
        __syncthreads();
    }
#pragma unroll
    for (int j = 0; j < 8; ++j)
        Ps[m * 132 + n0 + j] = fmaxf(acc[j] + bpr[n0 + j], 0.f);
    __syncthreads();

    const int j0 = g * 4;
    float acc2[4] = {0.f, 0.f, 0.f, 0.f};
    for (int n0c = 0; n0c < NH1; n0c += 32) {
        {   // Bs2[nn][j2] = W2[j2][n0c+nn] (stride 68)
            const int j2 = tid >> 2;
            const int no = (tid & 3) * 8;
#pragma unroll
            for (int i4 = 0; i4 < 2; ++i4) {
                const float4 v = *(const float4*)&W2[(size_t)j2 * NH1 + n0c + no + i4 * 4];
                Bs[(no + i4 * 4 + 0) * 68 + j2] = v.x;
                Bs[(no + i4 * 4 + 1) * 68 + j2] = v.y;
                Bs[(no + i4 * 4 + 2) * 68 + j2] = v.z;
                Bs[(no + i4 * 4 + 3) * 68 + j2] = v.w;
            }
        }
        __syncthreads();
#pragma unroll
        for (int nn = 0; nn < 32; ++nn) {
            const float p  = Ps[m * 132 + n0c + nn];
            const float4 w = *(const float4*)&Bs[nn * 68 + j0];
            acc2[0] = fmaf(p, w.x, acc2[0]);
            acc2[1] = fmaf(p, w.y, acc2[1]);
            acc2[2] = fmaf(p, w.z, acc2[2]);
            acc2[3] = fmaf(p, w.w, acc2[3]);
        }
        __syncthreads();
    }

    float po0 = 0.f, po1 = 0.f;
#pragma unroll
    for (int j = 0; j < 4; ++j) {
        const float h = fmaxf(acc2[j] + b2[j0 + j], 0.f);
        po0 = fmaf(h, Wo[j0 + j], po0);
        po1 = fmaf(h, Wo[NH2 + j0 + j], po1);
    }
    Rs[g * 32 + m * 2 + 0] = po0;
    Rs[g * 32 + m * 2 + 1] = po1;
    __syncthreads();
    if (tid < 32) {
        const int mm = tid >> 1, o = tid & 1;
        float sum = 0.f;
#pragma unroll
        for (int gg = 0; gg < 16; ++gg) sum += Rs[gg * 32 + mm * 2 + o];
        out[(size_t)(m0 + mm) * 2 + o] = sum + bo[o];
    }
}

extern "C" void kernel_launch(void* const* d_in, const int* in_sizes, int n_in,
                              void* d_out, int out_size, void* d_ws, size_t ws_size,
                              hipStream_t stream)
{
    const float* x   = (const float*)d_in[0];
    const float* W1  = (const float*)d_in[1];
    const float* b1  = (const float*)d_in[2];
    const float* Wpr = (const float*)d_in[3];
    const float* bpr = (const float*)d_in[4];
    const float* W2  = (const float*)d_in[5];
    const float* b2  = (const float*)d_in[6];
    const float* Wo  = (const float*)d_in[7];
    const float* bo  = (const float*)d_in[8];

    float* ws     = (float*)d_ws;
    float* h1T    = ws;                               // [128][4096]  2 MB
    float* sorted = h1T + NH1 * NB;                   // [128][4096]  2 MB
    float* prtT   = sorted + NH1 * NB;                // [128][4096]  2 MB
    _Float16* Whi = (_Float16*)(prtT + NH1 * NB);     // [128][1024]  256 KB
    _Float16* Wlo = Whi + NH1 * DIN;                  // [128][1024]  256 KB

    prep_w1<<<dim3(NH1 * DIN / 4 / 256), 256, 0, stream>>>(W1, Whi, Wlo);
    gemm1_mfma<<<dim3(NB / 16), 512, 0, stream>>>(x, Whi, Wlo, b1, h1T);
    sort_half_kernel<<<dim3(NH1 * 2), 512, 0, stream>>>(h1T, sorted);
    knn_merge_kernel<<<dim3(NH1 * 2), 1024, 0, stream>>>(h1T, sorted, prtT);
    tail_kernel<<<dim3(NB / 16), 256, 0, stream>>>(prtT, Wpr, bpr, W2, b2, Wo, bo,
                                                   (float*)d_out);
}